// Round 9
// baseline (477.457 us; speedup 1.0000x reference)
//
#include <hip/hip_runtime.h>

#define NPTS 8192
#define NB 4
#define NCH 128
#define DQK 48
#define TK 64
#define SPLIT 4
#define KEYS_PER (NPTS / SPLIT)   // 2048
#define ROUNDS (KEYS_PER / TK)    // 32
#define SH2 28.853901f            // 20 * log2(e)
#define LOG2E 1.4426950408889634f

typedef unsigned short ushort_t;
typedef unsigned int uint_t;
typedef __attribute__((ext_vector_type(8))) short bf16x8;
typedef __attribute__((ext_vector_type(2))) float f32x2;
typedef __attribute__((ext_vector_type(4))) float f32x4;
typedef __attribute__((ext_vector_type(16))) float f32x16;

static __device__ __forceinline__ ushort_t f2bf(float x) {
  union { float f; uint_t u; } v; v.f = x;
  uint_t r = v.u + 0x7fffu + ((v.u >> 16) & 1u);
  return (ushort_t)(r >> 16);
}
static __device__ __forceinline__ float bf2f(ushort_t u) {
  union { uint_t i; float f; } v; v.i = ((uint_t)u) << 16; return v.f;
}
// sigma16: swap middle two 4-blocks of each 16-group (involution).
// Makes S^T C-layout regs directly usable as the PV A-fragment.
static __device__ __forceinline__ int sig16(int n) {
  int g2 = (n >> 2) & 3;
  return (g2 == 1 || g2 == 2) ? (n ^ 0xC) : n;
}

typedef __attribute__((address_space(1))) void void_g;
typedef __attribute__((address_space(3))) void void_l;
static __device__ __forceinline__ void gload_lds16(const ushort_t* g, ushort_t* l) {
  __builtin_amdgcn_global_load_lds((void_g*)(ushort_t*)g, (void_l*)l, 16, 0, 0);
}

// ---------------------------------------------------------------------------
// FRAGMENT-MAJOR intermediate layouts:
//  Qb/Kb: [b][kblk = n>>5][c(3)][lane(64)][8]   (lane = (n&31) + 32*((d>>3)&1),
//         elem j = d&7, c = d>>4; d = 0..47, slots 32..47 hold xhat + shift)
//  Vt:    [b][mblk = np>>6][frag(16) = fch*4+kk][lane(64)][8]
//         (lane = (ch&31) + 32*((np>>3)&1), j = np&7; np = sig16-permuted key)
// All attn-side staging DMA sources are lane-contiguous 1KB bursts.
//
// R16 NOTE (post-mortem R15): split-K tail-fusion via __threadfence +
// arrival counter REGRESSED 2x (91->313us attn). Device-scope fences on
// gfx950 force per-XCD L2 writeback/invalidate; 512 staggered flushes
// destroyed K/V L2 residency for in-flight main loops (FETCH 8.7->34MB,
// MfmaUtil 47->12%). Kernel-boundary coherence is CHEAPER than in-kernel
// device fences at this granularity. Reverted to the 3-dispatch R14 form.
// ---------------------------------------------------------------------------

// ---------------------------------------------------------------------------
// MFMA projections. Each 32-pt tile's 6 bands split across two waves (half 0:
// z=0,1,2 / half 1: z=3,4,5): 512-thread blocks, 8 waves, 2048 waves total =
// 2 waves/SIMD. Wb A-frags + biases built in LDS per block; coalesced store
// path via per-wave 32x40 LDS transpose tile. Softmax shift folded into slot
// d=35: Q[35]=-SH2, K[35]=1.0 => attn exp2's directly.
// ---------------------------------------------------------------------------
#define TPITCH 40   // ushorts; 80B rows: 16B-aligned b128 reads, 2-way banks (free)
#define WBELEMS (6 * 8 * 64 * 8)   // 24576 ushorts = 48 KB
__global__ __launch_bounds__(512, 2)
void projm2_kernel(const float* __restrict__ x, const float* __restrict__ xyz,
                   const float* __restrict__ Wq, const float* __restrict__ bq,
                   const float* __restrict__ Wk, const float* __restrict__ bk,
                   const float* __restrict__ Wv, const float* __restrict__ bv,
                   ushort_t* __restrict__ Qb, ushort_t* __restrict__ Kb,
                   ushort_t* __restrict__ Vt) {
  __shared__ __align__(16) ushort_t WbL[WBELEMS];
  __shared__ float biasL[192];
  __shared__ __align__(16) ushort_t T[8][32 * TPITCH];
  const int tid = threadIdx.x;
  const int lane = tid & 63, wv = tid >> 6;      // wv = 0..7
  const int l31 = lane & 31, h = lane >> 5;
  const int b = blockIdx.y;
  const int tile = wv >> 1, half = wv & 1;       // 4 tiles x 2 band-halves
  const int n0 = blockIdx.x * 128 + tile * 32;
  const int n = n0 + l31;

  // B-frags from x (coalesced per c-row), converted once, reused 3x.
  // Issued first so their HBM latency overlaps the Wb build below.
  bf16x8 bfr[8];
  const float* xb = x + (size_t)b * NCH * NPTS + n;
#pragma unroll
  for (int ks = 0; ks < 8; ++ks) {
    const float* xc = xb + (size_t)(ks * 16 + h * 8) * NPTS;
    union { ushort_t u[8]; bf16x8 v; } p;
#pragma unroll
    for (int j = 0; j < 8; ++j) p.u[j] = f2bf(xc[(size_t)j * NPTS]);
    bfr[ks] = p.v;
  }

  // Build Wb fragments in LDS (log2e folded into z=0) + scaled biases.
#pragma unroll
  for (int it = 0; it < 6; ++it) {
    int slot = tid + it * 512;        // 0..3071 = (z*8+ks)*64 + ln
    int zk = slot >> 6, ln = slot & 63;
    int z = zk >> 3, ks = zk & 7;
    const float* W = (z == 0) ? Wq : (z == 1) ? Wk
                                              : (Wv + (size_t)(z - 2) * 32 * 128);
    const float sc = (z == 0) ? LOG2E : 1.0f;
    const float* wr = W + (ln & 31) * 128 + ks * 16 + (ln >> 5) * 8;
    union { ushort_t u[8]; bf16x8 v; } p;
#pragma unroll
    for (int j = 0; j < 8; ++j) p.u[j] = f2bf(wr[j] * sc);
    *(bf16x8*)(WbL + (size_t)slot * 8) = p.v;
  }
  if (tid < 192)
    biasL[tid] = (tid < 32) ? bq[tid] * LOG2E
                            : (tid < 64) ? bk[tid - 32] : bv[tid - 64];

  // xhat (used by half==0 only; loads are tiny)
  float xa = xyz[((size_t)b * NPTS + n) * 3 + 0];
  float xc2 = xyz[((size_t)b * NPTS + n) * 3 + 1];
  float xd = xyz[((size_t)b * NPTS + n) * 3 + 2];
  float rinv = 1.0f / (sqrtf(xa * xa + xc2 * xc2 + xd * xd) + 1e-8f);

  __syncthreads();

  const int nploc = (l31 & 16) | sig16(l31 & 15);  // V key position within tile
  ushort_t* tw = &T[wv][0];

#pragma unroll 1
  for (int zz = 0; zz < 3; ++zz) {
    const int z = half * 3 + zz;                  // half 0: 0,1,2 / half 1: 3,4,5
    f32x16 S;
#pragma unroll
    for (int r = 0; r < 16; ++r)
      S[r] = biasL[z * 32 + (r & 3) + 8 * (r >> 2) + 4 * h];
#pragma unroll
    for (int ks = 0; ks < 8; ++ks) {
      bf16x8 af = *(const bf16x8*)(WbL + ((size_t)(z * 8 + ks) * 64 + lane) * 8);
      S = __builtin_amdgcn_mfma_f32_32x32x16_bf16(af, bfr[ks], S, 0, 0, 0);
    }
    if (z <= 1) {
      // LDS tile [n31][d]: lane holds col n=l31, rows d=(r&3)+8*(r>>2)+4h
#pragma unroll
      for (int r = 0; r < 16; ++r)
        tw[l31 * TPITCH + (r & 3) + 8 * (r >> 2) + 4 * h] = f2bf(S[r]);
      ushort_t* dstf = (z == 0 ? Qb : Kb) +
                       (((size_t)b * 256 + (n0 >> 5)) * 3) * 512;
      // c=0,1 frags: lane = n31 + 32*hb, 8 consecutive d -> 16B read + store
#pragma unroll
      for (int c = 0; c < 2; ++c) {
        bf16x8 fr = *(const bf16x8*)&tw[(lane & 31) * TPITCH + c * 16 + (lane >> 5) * 8];
        *(bf16x8*)(dstf + c * 512 + lane * 8) = fr;
      }
      // c=2 frag: xhat + folded shift, register-direct (already frag-ordered)
      float sc = (z == 0) ? LOG2E : 1.0f;
      float rn = 0.31622776601683794f * sc * rinv;
      union { ushort_t u[16]; bf16x8 v[2]; } t;
#pragma unroll
      for (int j = 0; j < 16; ++j) t.u[j] = 0;
      t.u[0] = f2bf(xa * rn); t.u[1] = f2bf(xc2 * rn); t.u[2] = f2bf(xd * rn);
      t.u[3] = (z == 0) ? f2bf(-SH2) : f2bf(1.0f);  // folded softmax shift (d=35)
      *(bf16x8*)(dstf + 1024 + l31 * 8) = t.v[0];
      *(bf16x8*)(dstf + 1024 + 256 + l31 * 8) = t.v[1];
    } else {
      // LDS tile [ch31][nploc]: transpose n<->ch with sig16 folded in
#pragma unroll
      for (int r = 0; r < 16; ++r)
        tw[((r & 3) + 8 * (r >> 2) + 4 * h) * TPITCH + nploc] = f2bf(S[r]);
      // two complete fragments (16 keys x 32 ch each): coalesced 1KB stores
#pragma unroll
      for (int g = 0; g < 2; ++g) {
        bf16x8 fr = *(const bf16x8*)&tw[(lane & 31) * TPITCH + g * 16 + (lane >> 5) * 8];
        int kk = ((n0 >> 4) + g) & 3;
        ushort_t* dst = Vt + ((((size_t)b * 128 + (n0 >> 6)) * 16 +
                               (z - 2) * 4 + kk) * 512);
        *(bf16x8*)(dst + lane * 8) = fr;
      }
    }
  }
}

// ---------------------------------------------------------------------------
// MFMA flash attention, 32x32x16, 32 q/wave, 8 waves = 256 q/block.
// FROZEN at R12 structure (91us): all-LDS 22-frag staging w/ frag-major
// lane-contiguous 1KB DMA sources, 2-buffer/1-barrier, ~64 arch + 64 acc
// regs -> 4 waves/SIMD. R16 tweak: lsum accumulation split into 4
// independent partials (was a 16-deep serial add chain on the exp->PV
// critical path), folded at the epilogue.
// ---------------------------------------------------------------------------
__global__ __launch_bounds__(512, 4)
void attn32_kernel(const ushort_t* __restrict__ Qb, const ushort_t* __restrict__ Kb,
                   const ushort_t* __restrict__ Vt,
                   ushort_t* __restrict__ PACC, float* __restrict__ PL) {
  // frag f: V = fch*4+kk (0..15), K = 16 + kb*3 + c (16..21); 64 lanes x 16B
  __shared__ __align__(16) ushort_t L[2][22][512];
  const int tid = threadIdx.x;
  const int lane = tid & 63, w = tid >> 6;

  const int lin = blockIdx.x;
  const int bs = lin & 15;          // XCD x sees bs in {x, x+8}: 2 (b,seg) combos
  const int b = bs & 3, sseg = bs >> 2;
  const int qblk = lin >> 4;        // 0..31 (256-q blocks)
  const int q0w = qblk * 256 + w * 32;
  const int m00 = sseg * KEYS_PER;

  // persistent Q^T B-frags (frag-major, lane-contiguous)
  bf16x8 qf[3];
  {
    const ushort_t* qbase = Qb + (((size_t)b * 256 + (q0w >> 5)) * 3) * 512 + lane * 8;
#pragma unroll
    for (int c = 0; c < 3; ++c) qf[c] = *(const bf16x8*)(qbase + c * 512);
  }

  // staging sources (frag-major, lane-contiguous): wave w -> frags {w,w+8,w+16}
  const ushort_t* vbase = Vt + (((size_t)b * 128 + (m00 >> 6)) * 16) * 512 + lane * 8;
  const ushort_t* kbase = Kb + (((size_t)b * 256 + (m00 >> 5)) * 3) * 512 + lane * 8;
  const ushort_t* gp[3];
  int fid[3], adv[3];
  const int nf = (w < 6) ? 3 : 2;
#pragma unroll
  for (int i = 0; i < 3; ++i) {
    int fi = w + 8 * i;
    fid[i] = fi;
    if (fi < 16) { gp[i] = vbase + fi * 512; adv[i] = 16 * 512; }
    else if (fi < 22) { gp[i] = kbase + (fi - 16) * 512; adv[i] = 6 * 512; }
  }

  f32x16 O[4];
#pragma unroll
  for (int f = 0; f < 4; ++f) O[f] = (f32x16)(0.f);
  float lsp[4];
#pragma unroll
  for (int i = 0; i < 4; ++i) lsp[i] = 0.f;

  // prologue: stage round 0 into buffer 0
#pragma unroll
  for (int i = 0; i < 3; ++i)
    if (i < nf) gload_lds16(gp[i], &L[0][fid[i]][0]);

#pragma unroll 1
  for (int t = 0; t < ROUNDS; ++t) {
    __syncthreads();  // vmcnt(0): buf[t&1] DMA (issued a full round ago) drained
    const int cur = t & 1;
    if (t + 1 < ROUNDS) {
#pragma unroll
      for (int i = 0; i < 3; ++i)
        if (i < nf) {
          gp[i] += adv[i];
          gload_lds16(gp[i], &L[cur ^ 1][fid[i]][0]);  // overlaps compute below
        }
    }

#pragma unroll
    for (int kb = 0; kb < 2; ++kb) {
      bf16x8 kf0 = *(const bf16x8*)(&L[cur][16 + kb * 3 + 0][0] + lane * 8);
      bf16x8 kf1 = *(const bf16x8*)(&L[cur][16 + kb * 3 + 1][0] + lane * 8);
      bf16x8 kf2 = *(const bf16x8*)(&L[cur][16 + kb * 3 + 2][0] + lane * 8);

      __builtin_amdgcn_s_setprio(1);
      f32x16 S = __builtin_amdgcn_mfma_f32_32x32x16_bf16(kf0, qf[0],
                                                         (f32x16)(0.f), 0, 0, 0);
      S = __builtin_amdgcn_mfma_f32_32x32x16_bf16(kf1, qf[1], S, 0, 0, 0);
      S = __builtin_amdgcn_mfma_f32_32x32x16_bf16(kf2, qf[2], S, 0, 0, 0);
      __builtin_amdgcn_s_setprio(0);

      // shift already folded into S via slot 35: p = exp2(S) directly.
      // 4 independent lsum partials: no 16-deep serial add chain between
      // exp and the PV pack.
      uint_t pk[8];
#pragma unroll
      for (int i = 0; i < 8; ++i) {
        float p0 = __builtin_amdgcn_exp2f(S[2 * i]);
        float p1 = __builtin_amdgcn_exp2f(S[2 * i + 1]);
        lsp[i & 3] += p0 + p1;
        pk[i] = __builtin_amdgcn_perm(__float_as_uint(p1), __float_as_uint(p0),
                                      0x07060302u);
      }

      // sigma16-permuted V => C-regs pack directly into PV A-frags
#pragma unroll
      for (int kkl = 0; kkl < 2; ++kkl) {
        union { uint_t u[4]; bf16x8 v; } au;
        au.u[0] = pk[4 * kkl + 0];
        au.u[1] = pk[4 * kkl + 1];
        au.u[2] = pk[4 * kkl + 2];
        au.u[3] = pk[4 * kkl + 3];
        bf16x8 A = au.v;
        __builtin_amdgcn_s_setprio(1);
#pragma unroll
        for (int f = 0; f < 4; ++f) {
          bf16x8 vf = *(const bf16x8*)(&L[cur][f * 4 + kb * 2 + kkl][0] + lane * 8);
          O[f] = __builtin_amdgcn_mfma_f32_32x32x16_bf16(A, vf, O[f], 0, 0, 0);
        }
        __builtin_amdgcn_s_setprio(0);
      }
    }
  }

  // epilogue: global chunk id = bs*256 + (q>>5)
  float lsum = (lsp[0] + lsp[1]) + (lsp[2] + lsp[3]);
  lsum += __shfl_xor(lsum, 32);
  const size_t pbase = (size_t)(bs * 16 + (qblk >> 1)) * 16 + (qblk & 1) * 8 + w;
#pragma unroll
  for (int f = 0; f < 4; ++f) {
    union { ushort_t u[16]; bf16x8 v[2]; } pu;
#pragma unroll
    for (int r = 0; r < 16; ++r) pu.u[r] = f2bf(O[f][r]);
    size_t idx = (pbase * 4 + f) * 1024 + (size_t)lane * 16;
    *(bf16x8*)(PACC + idx) = pu.v[0];
    *(bf16x8*)(PACC + idx + 8) = pu.v[1];
  }
  if (lane < 32) PL[(size_t)bs * NPTS + q0w + lane] = lsum;
}

// ---------------------------------------------------------------------------
// Merge 4 key-split partials + gamma + x, COALESCED output via LDS bounce.
// 128-q blocks, grid (64,4,4) = 1024 blocks -> 4 blocks/CU, 16 waves/CU.
// Phase 1: wave ww owns chunk (q0>>5)+ww: coalesced PACC reads, sum over s,
// x Linv, stage fp32 in LDS. Phase 2: wave -> 8 ch rows, lane -> q=lane*2.
// ---------------------------------------------------------------------------
#define MP2 132
__global__ __launch_bounds__(256, 4)
void merge4c_kernel(const ushort_t* __restrict__ PACC, const float* __restrict__ PL,
                    const float* __restrict__ x, const float* __restrict__ gamma,
                    float* __restrict__ out) {
  __shared__ float Linv[128];
  __shared__ float ldso[32 * MP2];
  const int tid = threadIdx.x;
  const int qb = blockIdx.x, b = blockIdx.y, f = blockIdx.z;
  const int q0 = qb * 128;

  if (tid < 128) {
    float Ls = 0.f;
#pragma unroll
    for (int s = 0; s < 4; ++s)
      Ls += PL[(size_t)(s * 4 + b) * NPTS + q0 + tid];
    Linv[tid] = gamma[0] / Ls;
  }
  __syncthreads();

  const int ww = tid >> 6, lane = tid & 63, l31 = lane & 31, h = lane >> 5;

  // wave ww owns global chunk (s*4+b)*256 + (q0>>5) + ww (32 q x 32 ch)
  float acc[16];
#pragma unroll
  for (int r = 0; r < 16; ++r) acc[r] = 0.f;
#pragma unroll
  for (int s = 0; s < 4; ++s) {
    size_t idx = (((size_t)(s * 4 + b) * 256 + (q0 >> 5) + ww) * 4 + f) * 1024 +
                 (size_t)lane * 16;
    bf16x8 a0 = *(const bf16x8*)(PACC + idx);
    bf16x8 a1 = *(const bf16x8*)(PACC + idx + 8);
#pragma unroll
    for (int r = 0; r < 8; ++r) {
      acc[r] += bf2f((ushort_t)a0[r]);
      acc[8 + r] += bf2f((ushort_t)a1[r]);
    }
  }
  const int qloc = ww * 32 + 4 * h;
#pragma unroll
  for (int rr = 0; rr < 4; ++rr) {
    int q = qloc + 8 * rr;
    f32x4 v;
#pragma unroll
    for (int i = 0; i < 4; ++i) v[i] = acc[rr * 4 + i] * Linv[q + i];
    *(f32x4*)&ldso[l31 * MP2 + q] = v;  // ch_local = l31
  }
  __syncthreads();

  // phase 2: coalesced: wave ww -> ch rows ww*8..+7, lane -> q = lane*2
  const float* xb = x + ((size_t)b * NCH + f * 32) * NPTS + q0;
  float* ob = out + ((size_t)b * NCH + f * 32) * NPTS + q0;
#pragma unroll
  for (int rr = 0; rr < 8; ++rr) {
    int ch = ww * 8 + rr;
    f32x2 v = *(const f32x2*)&ldso[ch * MP2 + lane * 2];
    f32x2 xv = *(const f32x2*)(xb + (size_t)ch * NPTS + lane * 2);
    v += xv;
    *(f32x2*)(ob + (size_t)ch * NPTS + lane * 2) = v;
  }
}

// ---------------------------------------------------------------------------
extern "C" void kernel_launch(void* const* d_in, const int* in_sizes, int n_in,
                              void* d_out, int out_size, void* d_ws,
                              size_t ws_size, hipStream_t stream) {
  const float* x     = (const float*)d_in[0];
  const float* xyz   = (const float*)d_in[1];
  const float* Wq    = (const float*)d_in[2];
  const float* bq    = (const float*)d_in[3];
  const float* Wk    = (const float*)d_in[4];
  const float* bk    = (const float*)d_in[5];
  const float* Wv    = (const float*)d_in[6];
  const float* bv    = (const float*)d_in[7];
  const float* gamma = (const float*)d_in[8];
  float* out = (float*)d_out;

  const size_t BN = (size_t)NB * NPTS;
  ushort_t* Qb = (ushort_t*)d_ws;                 // 4*256*3*512 = BN*DQK
  ushort_t* Kb = Qb + BN * DQK;
  ushort_t* Vt = Kb + BN * DQK;                   // 4*128*16*512 = BN*NCH
  ushort_t* PACC = Vt + BN * NCH;   // 16 bs * 256 chunk * 4 f * 1024
  float* PL = (float*)(PACC + (size_t)16 * 16 * 8 * 2 * 4 * 1024);

  projm2_kernel<<<dim3(NPTS / 128, NB), 512, 0, stream>>>(
      x, xyz, Wq, bq, Wk, bk, Wv, bv, Qb, Kb, Vt);
  attn32_kernel<<<512, 512, 0, stream>>>(Qb, Kb, Vt, PACC, PL);
  merge4c_kernel<<<dim3(64, NB, 4), 256, 0, stream>>>(PACC, PL, x, gamma, out);
  (void)in_sizes; (void)n_in; (void)out_size; (void)ws_size;
}

// Round 10
// 178.712 us; speedup vs baseline: 2.6717x; 2.6717x over previous
//
#include <hip/hip_runtime.h>

#define NPTS 8192
#define NB 4
#define NCH 128
#define DQK 48
#define TK 64
#define SPLIT 4
#define KEYS_PER (NPTS / SPLIT)   // 2048
#define ROUNDS (KEYS_PER / TK)    // 32
#define SH2 28.853901f            // 20 * log2(e)
#define LOG2E 1.4426950408889634f

typedef unsigned short ushort_t;
typedef unsigned int uint_t;
typedef __attribute__((ext_vector_type(8))) short bf16x8;
typedef __attribute__((ext_vector_type(2))) float f32x2;
typedef __attribute__((ext_vector_type(4))) float f32x4;
typedef __attribute__((ext_vector_type(16))) float f32x16;

static __device__ __forceinline__ ushort_t f2bf(float x) {
  union { float f; uint_t u; } v; v.f = x;
  uint_t r = v.u + 0x7fffu + ((v.u >> 16) & 1u);
  return (ushort_t)(r >> 16);
}
static __device__ __forceinline__ float bf2f(ushort_t u) {
  union { uint_t i; float f; } v; v.i = ((uint_t)u) << 16; return v.f;
}
// sigma16: swap middle two 4-blocks of each 16-group (involution).
// Makes S^T C-layout regs directly usable as the PV A-fragment.
static __device__ __forceinline__ int sig16(int n) {
  int g2 = (n >> 2) & 3;
  return (g2 == 1 || g2 == 2) ? (n ^ 0xC) : n;
}

typedef __attribute__((address_space(1))) void void_g;
typedef __attribute__((address_space(3))) void void_l;
static __device__ __forceinline__ void gload_lds16(const ushort_t* g, ushort_t* l) {
  __builtin_amdgcn_global_load_lds((void_g*)(ushort_t*)g, (void_l*)l, 16, 0, 0);
}

// ---------------------------------------------------------------------------
// FRAGMENT-MAJOR intermediate layouts:
//  Qb/Kb: [b][kblk = n>>5][c(3)][lane(64)][8]   (lane = (n&31) + 32*((d>>3)&1),
//         elem j = d&7, c = d>>4; d = 0..47, slots 32..47 hold xhat + shift)
//  Vt:    [b][mblk = np>>6][frag(16) = fch*4+kk][lane(64)][8]
//         (lane = (ch&31) + 32*((np>>3)&1), j = np&7; np = sig16-permuted key)
// All attn-side staging DMA sources are lane-contiguous 1KB bursts.
//
// R17 NOTE (post-mortems R15/R16):
//  - R15 split-K tail-fusion via __threadfence + arrival counter regressed
//    2x: device-scope fences force per-XCD L2 writeback/invalidate; 512
//    staggered flushes destroyed K/V L2 residency (FETCH 8.7->34MB).
//    Kernel-boundary coherence is CHEAPER than in-kernel device fences.
//  - R16 "float lsp[4]" accumulator was demoted to SCRATCH (rule #20):
//    FETCH 728MB / WRITE 1.08GB of spill traffic, attn 91->381us. Hot
//    accumulators must be NAMED SCALARS (ls0/ls1), never small arrays.
// This file is the byte-identical R14 form (best measured: 184.5us total).
// ---------------------------------------------------------------------------

// ---------------------------------------------------------------------------
// MFMA projections. Each 32-pt tile's 6 bands split across two waves (half 0:
// z=0,1,2 / half 1: z=3,4,5): 512-thread blocks, 8 waves, 2048 waves total =
// 2 waves/SIMD. Wb A-frags + biases built in LDS per block; coalesced store
// path via per-wave 32x40 LDS transpose tile. Softmax shift folded into slot
// d=35: Q[35]=-SH2, K[35]=1.0 => attn exp2's directly.
// ---------------------------------------------------------------------------
#define TPITCH 40   // ushorts; 80B rows: 16B-aligned b128 reads, 2-way banks (free)
#define WBELEMS (6 * 8 * 64 * 8)   // 24576 ushorts = 48 KB
__global__ __launch_bounds__(512, 2)
void projm2_kernel(const float* __restrict__ x, const float* __restrict__ xyz,
                   const float* __restrict__ Wq, const float* __restrict__ bq,
                   const float* __restrict__ Wk, const float* __restrict__ bk,
                   const float* __restrict__ Wv, const float* __restrict__ bv,
                   ushort_t* __restrict__ Qb, ushort_t* __restrict__ Kb,
                   ushort_t* __restrict__ Vt) {
  __shared__ __align__(16) ushort_t WbL[WBELEMS];
  __shared__ float biasL[192];
  __shared__ __align__(16) ushort_t T[8][32 * TPITCH];
  const int tid = threadIdx.x;
  const int lane = tid & 63, wv = tid >> 6;      // wv = 0..7
  const int l31 = lane & 31, h = lane >> 5;
  const int b = blockIdx.y;
  const int tile = wv >> 1, half = wv & 1;       // 4 tiles x 2 band-halves
  const int n0 = blockIdx.x * 128 + tile * 32;
  const int n = n0 + l31;

  // B-frags from x (coalesced per c-row), converted once, reused 3x.
  // Issued first so their HBM latency overlaps the Wb build below.
  bf16x8 bfr[8];
  const float* xb = x + (size_t)b * NCH * NPTS + n;
#pragma unroll
  for (int ks = 0; ks < 8; ++ks) {
    const float* xc = xb + (size_t)(ks * 16 + h * 8) * NPTS;
    union { ushort_t u[8]; bf16x8 v; } p;
#pragma unroll
    for (int j = 0; j < 8; ++j) p.u[j] = f2bf(xc[(size_t)j * NPTS]);
    bfr[ks] = p.v;
  }

  // Build Wb fragments in LDS (log2e folded into z=0) + scaled biases.
#pragma unroll
  for (int it = 0; it < 6; ++it) {
    int slot = tid + it * 512;        // 0..3071 = (z*8+ks)*64 + ln
    int zk = slot >> 6, ln = slot & 63;
    int z = zk >> 3, ks = zk & 7;
    const float* W = (z == 0) ? Wq : (z == 1) ? Wk
                                              : (Wv + (size_t)(z - 2) * 32 * 128);
    const float sc = (z == 0) ? LOG2E : 1.0f;
    const float* wr = W + (ln & 31) * 128 + ks * 16 + (ln >> 5) * 8;
    union { ushort_t u[8]; bf16x8 v; } p;
#pragma unroll
    for (int j = 0; j < 8; ++j) p.u[j] = f2bf(wr[j] * sc);
    *(bf16x8*)(WbL + (size_t)slot * 8) = p.v;
  }
  if (tid < 192)
    biasL[tid] = (tid < 32) ? bq[tid] * LOG2E
                            : (tid < 64) ? bk[tid - 32] : bv[tid - 64];

  // xhat (used by half==0 only; loads are tiny)
  float xa = xyz[((size_t)b * NPTS + n) * 3 + 0];
  float xc2 = xyz[((size_t)b * NPTS + n) * 3 + 1];
  float xd = xyz[((size_t)b * NPTS + n) * 3 + 2];
  float rinv = 1.0f / (sqrtf(xa * xa + xc2 * xc2 + xd * xd) + 1e-8f);

  __syncthreads();

  const int nploc = (l31 & 16) | sig16(l31 & 15);  // V key position within tile
  ushort_t* tw = &T[wv][0];

#pragma unroll 1
  for (int zz = 0; zz < 3; ++zz) {
    const int z = half * 3 + zz;                  // half 0: 0,1,2 / half 1: 3,4,5
    f32x16 S;
#pragma unroll
    for (int r = 0; r < 16; ++r)
      S[r] = biasL[z * 32 + (r & 3) + 8 * (r >> 2) + 4 * h];
#pragma unroll
    for (int ks = 0; ks < 8; ++ks) {
      bf16x8 af = *(const bf16x8*)(WbL + ((size_t)(z * 8 + ks) * 64 + lane) * 8);
      S = __builtin_amdgcn_mfma_f32_32x32x16_bf16(af, bfr[ks], S, 0, 0, 0);
    }
    if (z <= 1) {
      // LDS tile [n31][d]: lane holds col n=l31, rows d=(r&3)+8*(r>>2)+4h
#pragma unroll
      for (int r = 0; r < 16; ++r)
        tw[l31 * TPITCH + (r & 3) + 8 * (r >> 2) + 4 * h] = f2bf(S[r]);
      ushort_t* dstf = (z == 0 ? Qb : Kb) +
                       (((size_t)b * 256 + (n0 >> 5)) * 3) * 512;
      // c=0,1 frags: lane = n31 + 32*hb, 8 consecutive d -> 16B read + store
#pragma unroll
      for (int c = 0; c < 2; ++c) {
        bf16x8 fr = *(const bf16x8*)&tw[(lane & 31) * TPITCH + c * 16 + (lane >> 5) * 8];
        *(bf16x8*)(dstf + c * 512 + lane * 8) = fr;
      }
      // c=2 frag: xhat + folded shift, register-direct (already frag-ordered)
      float sc = (z == 0) ? LOG2E : 1.0f;
      float rn = 0.31622776601683794f * sc * rinv;
      union { ushort_t u[16]; bf16x8 v[2]; } t;
#pragma unroll
      for (int j = 0; j < 16; ++j) t.u[j] = 0;
      t.u[0] = f2bf(xa * rn); t.u[1] = f2bf(xc2 * rn); t.u[2] = f2bf(xd * rn);
      t.u[3] = (z == 0) ? f2bf(-SH2) : f2bf(1.0f);  // folded softmax shift (d=35)
      *(bf16x8*)(dstf + 1024 + l31 * 8) = t.v[0];
      *(bf16x8*)(dstf + 1024 + 256 + l31 * 8) = t.v[1];
    } else {
      // LDS tile [ch31][nploc]: transpose n<->ch with sig16 folded in
#pragma unroll
      for (int r = 0; r < 16; ++r)
        tw[((r & 3) + 8 * (r >> 2) + 4 * h) * TPITCH + nploc] = f2bf(S[r]);
      // two complete fragments (16 keys x 32 ch each): coalesced 1KB stores
#pragma unroll
      for (int g = 0; g < 2; ++g) {
        bf16x8 fr = *(const bf16x8*)&tw[(lane & 31) * TPITCH + g * 16 + (lane >> 5) * 8];
        int kk = ((n0 >> 4) + g) & 3;
        ushort_t* dst = Vt + ((((size_t)b * 128 + (n0 >> 6)) * 16 +
                               (z - 2) * 4 + kk) * 512);
        *(bf16x8*)(dst + lane * 8) = fr;
      }
    }
  }
}

// ---------------------------------------------------------------------------
// MFMA flash attention, 32x32x16, 32 q/wave, 8 waves = 256 q/block.
// FROZEN at R12 structure (91us): all-LDS 22-frag staging w/ frag-major
// lane-contiguous 1KB DMA sources, 2-buffer/1-barrier, ~64 arch + 64 acc
// regs -> 4 waves/SIMD. lsum accumulators are NAMED SCALARS ls0/ls1 —
// R16's lsp[4] array was demoted to scratch (rule #20) and cost 4x.
// ---------------------------------------------------------------------------
__global__ __launch_bounds__(512, 4)
void attn32_kernel(const ushort_t* __restrict__ Qb, const ushort_t* __restrict__ Kb,
                   const ushort_t* __restrict__ Vt,
                   ushort_t* __restrict__ PACC, float* __restrict__ PL) {
  // frag f: V = fch*4+kk (0..15), K = 16 + kb*3 + c (16..21); 64 lanes x 16B
  __shared__ __align__(16) ushort_t L[2][22][512];
  const int tid = threadIdx.x;
  const int lane = tid & 63, w = tid >> 6;

  const int lin = blockIdx.x;
  const int bs = lin & 15;          // XCD x sees bs in {x, x+8}: 2 (b,seg) combos
  const int b = bs & 3, sseg = bs >> 2;
  const int qblk = lin >> 4;        // 0..31 (256-q blocks)
  const int q0w = qblk * 256 + w * 32;
  const int m00 = sseg * KEYS_PER;

  // persistent Q^T B-frags (frag-major, lane-contiguous)
  bf16x8 qf[3];
  {
    const ushort_t* qbase = Qb + (((size_t)b * 256 + (q0w >> 5)) * 3) * 512 + lane * 8;
#pragma unroll
    for (int c = 0; c < 3; ++c) qf[c] = *(const bf16x8*)(qbase + c * 512);
  }

  // staging sources (frag-major, lane-contiguous): wave w -> frags {w,w+8,w+16}
  const ushort_t* vbase = Vt + (((size_t)b * 128 + (m00 >> 6)) * 16) * 512 + lane * 8;
  const ushort_t* kbase = Kb + (((size_t)b * 256 + (m00 >> 5)) * 3) * 512 + lane * 8;
  const ushort_t* gp[3];
  int fid[3], adv[3];
  const int nf = (w < 6) ? 3 : 2;
#pragma unroll
  for (int i = 0; i < 3; ++i) {
    int fi = w + 8 * i;
    fid[i] = fi;
    if (fi < 16) { gp[i] = vbase + fi * 512; adv[i] = 16 * 512; }
    else if (fi < 22) { gp[i] = kbase + (fi - 16) * 512; adv[i] = 6 * 512; }
  }

  f32x16 O[4];
#pragma unroll
  for (int f = 0; f < 4; ++f) O[f] = (f32x16)(0.f);
  float ls0 = 0.f, ls1 = 0.f;

  // prologue: stage round 0 into buffer 0
#pragma unroll
  for (int i = 0; i < 3; ++i)
    if (i < nf) gload_lds16(gp[i], &L[0][fid[i]][0]);

#pragma unroll 1
  for (int t = 0; t < ROUNDS; ++t) {
    __syncthreads();  // vmcnt(0): buf[t&1] DMA (issued a full round ago) drained
    const int cur = t & 1;
    if (t + 1 < ROUNDS) {
#pragma unroll
      for (int i = 0; i < 3; ++i)
        if (i < nf) {
          gp[i] += adv[i];
          gload_lds16(gp[i], &L[cur ^ 1][fid[i]][0]);  // overlaps compute below
        }
    }

#pragma unroll
    for (int kb = 0; kb < 2; ++kb) {
      bf16x8 kf0 = *(const bf16x8*)(&L[cur][16 + kb * 3 + 0][0] + lane * 8);
      bf16x8 kf1 = *(const bf16x8*)(&L[cur][16 + kb * 3 + 1][0] + lane * 8);
      bf16x8 kf2 = *(const bf16x8*)(&L[cur][16 + kb * 3 + 2][0] + lane * 8);

      __builtin_amdgcn_s_setprio(1);
      f32x16 S = __builtin_amdgcn_mfma_f32_32x32x16_bf16(kf0, qf[0],
                                                         (f32x16)(0.f), 0, 0, 0);
      S = __builtin_amdgcn_mfma_f32_32x32x16_bf16(kf1, qf[1], S, 0, 0, 0);
      S = __builtin_amdgcn_mfma_f32_32x32x16_bf16(kf2, qf[2], S, 0, 0, 0);
      __builtin_amdgcn_s_setprio(0);

      // shift already folded into S via slot 35: p = exp2(S) directly
      uint_t pk[8];
#pragma unroll
      for (int i = 0; i < 8; ++i) {
        float p0 = __builtin_amdgcn_exp2f(S[2 * i]);
        float p1 = __builtin_amdgcn_exp2f(S[2 * i + 1]);
        ls0 += p0;
        ls1 += p1;
        pk[i] = __builtin_amdgcn_perm(__float_as_uint(p1), __float_as_uint(p0),
                                      0x07060302u);
      }

      // sigma16-permuted V => C-regs pack directly into PV A-frags
#pragma unroll
      for (int kkl = 0; kkl < 2; ++kkl) {
        union { uint_t u[4]; bf16x8 v; } au;
        au.u[0] = pk[4 * kkl + 0];
        au.u[1] = pk[4 * kkl + 1];
        au.u[2] = pk[4 * kkl + 2];
        au.u[3] = pk[4 * kkl + 3];
        bf16x8 A = au.v;
        __builtin_amdgcn_s_setprio(1);
#pragma unroll
        for (int f = 0; f < 4; ++f) {
          bf16x8 vf = *(const bf16x8*)(&L[cur][f * 4 + kb * 2 + kkl][0] + lane * 8);
          O[f] = __builtin_amdgcn_mfma_f32_32x32x16_bf16(A, vf, O[f], 0, 0, 0);
        }
        __builtin_amdgcn_s_setprio(0);
      }
    }
  }

  // epilogue: global chunk id = bs*256 + (q>>5)
  float lsum = ls0 + ls1;
  lsum += __shfl_xor(lsum, 32);
  const size_t pbase = (size_t)(bs * 16 + (qblk >> 1)) * 16 + (qblk & 1) * 8 + w;
#pragma unroll
  for (int f = 0; f < 4; ++f) {
    union { ushort_t u[16]; bf16x8 v[2]; } pu;
#pragma unroll
    for (int r = 0; r < 16; ++r) pu.u[r] = f2bf(O[f][r]);
    size_t idx = (pbase * 4 + f) * 1024 + (size_t)lane * 16;
    *(bf16x8*)(PACC + idx) = pu.v[0];
    *(bf16x8*)(PACC + idx + 8) = pu.v[1];
  }
  if (lane < 32) PL[(size_t)bs * NPTS + q0w + lane] = lsum;
}

// ---------------------------------------------------------------------------
// Merge 4 key-split partials + gamma + x, COALESCED output via LDS bounce.
// 128-q blocks, grid (64,4,4) = 1024 blocks -> 4 blocks/CU, 16 waves/CU.
// Phase 1: wave ww owns chunk (q0>>5)+ww: coalesced PACC reads, sum over s,
// x Linv, stage fp32 in LDS. Phase 2: wave -> 8 ch rows, lane -> q=lane*2.
// ---------------------------------------------------------------------------
#define MP2 132
__global__ __launch_bounds__(256, 4)
void merge4c_kernel(const ushort_t* __restrict__ PACC, const float* __restrict__ PL,
                    const float* __restrict__ x, const float* __restrict__ gamma,
                    float* __restrict__ out) {
  __shared__ float Linv[128];
  __shared__ float ldso[32 * MP2];
  const int tid = threadIdx.x;
  const int qb = blockIdx.x, b = blockIdx.y, f = blockIdx.z;
  const int q0 = qb * 128;

  if (tid < 128) {
    float Ls = 0.f;
#pragma unroll
    for (int s = 0; s < 4; ++s)
      Ls += PL[(size_t)(s * 4 + b) * NPTS + q0 + tid];
    Linv[tid] = gamma[0] / Ls;
  }
  __syncthreads();

  const int ww = tid >> 6, lane = tid & 63, l31 = lane & 31, h = lane >> 5;

  // wave ww owns global chunk (s*4+b)*256 + (q0>>5) + ww (32 q x 32 ch)
  float acc[16];
#pragma unroll
  for (int r = 0; r < 16; ++r) acc[r] = 0.f;
#pragma unroll
  for (int s = 0; s < 4; ++s) {
    size_t idx = (((size_t)(s * 4 + b) * 256 + (q0 >> 5) + ww) * 4 + f) * 1024 +
                 (size_t)lane * 16;
    bf16x8 a0 = *(const bf16x8*)(PACC + idx);
    bf16x8 a1 = *(const bf16x8*)(PACC + idx + 8);
#pragma unroll
    for (int r = 0; r < 8; ++r) {
      acc[r] += bf2f((ushort_t)a0[r]);
      acc[8 + r] += bf2f((ushort_t)a1[r]);
    }
  }
  const int qloc = ww * 32 + 4 * h;
#pragma unroll
  for (int rr = 0; rr < 4; ++rr) {
    int q = qloc + 8 * rr;
    f32x4 v;
#pragma unroll
    for (int i = 0; i < 4; ++i) v[i] = acc[rr * 4 + i] * Linv[q + i];
    *(f32x4*)&ldso[l31 * MP2 + q] = v;  // ch_local = l31
  }
  __syncthreads();

  // phase 2: coalesced: wave ww -> ch rows ww*8..+7, lane -> q = lane*2
  const float* xb = x + ((size_t)b * NCH + f * 32) * NPTS + q0;
  float* ob = out + ((size_t)b * NCH + f * 32) * NPTS + q0;
#pragma unroll
  for (int rr = 0; rr < 8; ++rr) {
    int ch = ww * 8 + rr;
    f32x2 v = *(const f32x2*)&ldso[ch * MP2 + lane * 2];
    f32x2 xv = *(const f32x2*)(xb + (size_t)ch * NPTS + lane * 2);
    v += xv;
    *(f32x2*)(ob + (size_t)ch * NPTS + lane * 2) = v;
  }
}

// ---------------------------------------------------------------------------
extern "C" void kernel_launch(void* const* d_in, const int* in_sizes, int n_in,
                              void* d_out, int out_size, void* d_ws,
                              size_t ws_size, hipStream_t stream) {
  const float* x     = (const float*)d_in[0];
  const float* xyz   = (const float*)d_in[1];
  const float* Wq    = (const float*)d_in[2];
  const float* bq    = (const float*)d_in[3];
  const float* Wk    = (const float*)d_in[4];
  const float* bk    = (const float*)d_in[5];
  const float* Wv    = (const float*)d_in[6];
  const float* bv    = (const float*)d_in[7];
  const float* gamma = (const float*)d_in[8];
  float* out = (float*)d_out;

  const size_t BN = (size_t)NB * NPTS;
  ushort_t* Qb = (ushort_t*)d_ws;                 // 4*256*3*512 = BN*DQK
  ushort_t* Kb = Qb + BN * DQK;
  ushort_t* Vt = Kb + BN * DQK;                   // 4*128*16*512 = BN*NCH
  ushort_t* PACC = Vt + BN * NCH;   // 16 bs * 256 chunk * 4 f * 1024
  float* PL = (float*)(PACC + (size_t)16 * 16 * 8 * 2 * 4 * 1024);

  projm2_kernel<<<dim3(NPTS / 128, NB), 512, 0, stream>>>(
      x, xyz, Wq, bq, Wk, bk, Wv, bv, Qb, Kb, Vt);
  attn32_kernel<<<512, 512, 0, stream>>>(Qb, Kb, Vt, PACC, PL);
  merge4c_kernel<<<dim3(64, NB, 4), 256, 0, stream>>>(PACC, PL, x, gamma, out);
  (void)in_sizes; (void)n_in; (void)out_size; (void)ws_size;
}